// Round 1
// baseline (578.278 us; speedup 1.0000x reference)
//
#include <hip/hip_runtime.h>

#define LDS_S 132   // 128 + 4 floats pad: breaks quad-bank aliasing for float4 LDS reads

// ---------------------------------------------------------------------------
// Kernel 1: fused QKV projection.  Q=h@Wq^T, K=h@Wk^T, V=h@Wv^T.
// Block = 256 threads, 64 rows.  Weight staged in two 64-row halves (LDS
// 67.5 KB total -> 2 blocks/CU).  Thread (r=t/16, c=t%16) computes rows
// 4r..4r+3 x cols {c+16j} per half.  4x4 micro-tile per half, float4 k-unroll.
// ---------------------------------------------------------------------------
__global__ __launch_bounds__(256) void qkv_kernel(
    const float* __restrict__ h,
    const float* __restrict__ Wq, const float* __restrict__ Wk,
    const float* __restrict__ Wv,
    float* __restrict__ Q, float* __restrict__ K, float* __restrict__ V,
    int N)
{
    __shared__ float hs[64 * LDS_S];
    __shared__ float ws[64 * LDS_S];
    const int t = threadIdx.x;
    const int row0 = blockIdx.x * 64;

    // stage h tile (contiguous 8192 floats), zero-fill past N
    const float* hblk = h + (size_t)row0 * 128;
    #pragma unroll
    for (int jj = 0; jj < 8; ++jj) {
        int e = t * 4 + jj * 1024;
        int rr = e >> 7, cc = e & 127;
        float4 val = make_float4(0.f, 0.f, 0.f, 0.f);
        if (row0 + rr < N) val = *(const float4*)(hblk + e);
        *(float4*)&hs[rr * LDS_S + cc] = val;
    }

    const int r = t >> 4;   // 0..15  (row group)
    const int c = t & 15;   // 0..15  (col lane)

    const float* Wmats[3] = {Wq, Wk, Wv};
    float* Outs[3] = {Q, K, V};

    for (int w = 0; w < 3; ++w) {
        const float* W = Wmats[w];
        float acc[4][8];
        #pragma unroll
        for (int i = 0; i < 4; ++i)
            #pragma unroll
            for (int j = 0; j < 8; ++j) acc[i][j] = 0.f;

        for (int half = 0; half < 2; ++half) {
            __syncthreads();
            const float* Wh = W + half * 64 * 128;
            #pragma unroll
            for (int jj = 0; jj < 8; ++jj) {
                int e = t * 4 + jj * 1024;
                int o = e >> 7, kk = e & 127;
                *(float4*)&ws[o * LDS_S + kk] = *(const float4*)(Wh + e);
            }
            __syncthreads();

            for (int k = 0; k < 128; k += 4) {
                float4 a[4], b[4];
                #pragma unroll
                for (int i = 0; i < 4; ++i)
                    a[i] = *(const float4*)&hs[(4 * r + i) * LDS_S + k];
                #pragma unroll
                for (int j = 0; j < 4; ++j)
                    b[j] = *(const float4*)&ws[(c + 16 * j) * LDS_S + k];
                #pragma unroll
                for (int i = 0; i < 4; ++i)
                    #pragma unroll
                    for (int j = 0; j < 4; ++j) {
                        float* ac = &acc[i][half * 4 + j];
                        *ac += a[i].x * b[j].x;
                        *ac += a[i].y * b[j].y;
                        *ac += a[i].z * b[j].z;
                        *ac += a[i].w * b[j].w;
                    }
            }
        }
        // store: col(j) = (j>>2)*64 + (j&3)*16 + c
        float* O = Outs[w];
        #pragma unroll
        for (int i = 0; i < 4; ++i) {
            int row = row0 + 4 * r + i;
            if (row < N) {
                #pragma unroll
                for (int j = 0; j < 8; ++j) {
                    int col = ((j >> 2) << 6) + ((j & 3) << 4) + c;
                    O[(size_t)row * 128 + col] = acc[i][j];
                }
            }
        }
    }
}

// ---------------------------------------------------------------------------
// Kernel 2: neighbor attention.  One wave per node; lane handles dims
// [2*lane, 2*lane+1] -> lanes 8h..8h+7 cover head h.  shfl_xor(1,2,4)
// reduces the per-head dot; softmax over 16 neighbors in-register.
// A may alias Q (q loaded to registers before the final store).
// ---------------------------------------------------------------------------
__global__ __launch_bounds__(256) void attn_kernel(
    const float* Q, const float* __restrict__ K, const float* __restrict__ V,
    const int* __restrict__ nbr, float* A, int N)
{
    int gid = blockIdx.x * blockDim.x + threadIdx.x;
    int n = gid >> 6;
    int lane = threadIdx.x & 63;
    if (n >= N) return;

    float2 q = *(const float2*)&Q[(size_t)n * 128 + 2 * lane];

    int idx[16];
    #pragma unroll
    for (int j = 0; j < 16; ++j) idx[j] = nbr[n * 16 + j];

    float logit[16];
    #pragma unroll
    for (int j = 0; j < 16; ++j) {
        float2 kv = *(const float2*)&K[(size_t)idx[j] * 128 + 2 * lane];
        float s = q.x * kv.x + q.y * kv.y;
        s += __shfl_xor(s, 1);
        s += __shfl_xor(s, 2);
        s += __shfl_xor(s, 4);
        logit[j] = s * 0.25f;   // D^-0.5 = 1/4
    }

    float m = logit[0];
    #pragma unroll
    for (int j = 1; j < 16; ++j) m = fmaxf(m, logit[j]);
    float sum = 0.f;
    #pragma unroll
    for (int j = 0; j < 16; ++j) { logit[j] = __expf(logit[j] - m); sum += logit[j]; }
    float inv = 1.f / sum;

    float2 acc = make_float2(0.f, 0.f);
    #pragma unroll
    for (int j = 0; j < 16; ++j) {
        float2 v2 = *(const float2*)&V[(size_t)idx[j] * 128 + 2 * lane];
        float p = logit[j] * inv;
        acc.x += p * v2.x;
        acc.y += p * v2.y;
    }
    *(float2*)&A[(size_t)n * 128 + 2 * lane] = acc;
}

// ---------------------------------------------------------------------------
// Kernel 3: out = A@Wo^T + bo; x = h + out; LayerNorm(x)*gamma + beta.
// Same tiling as kernel 1; LN row-reduce via shfl_xor over the 16 col lanes.
// ---------------------------------------------------------------------------
__global__ __launch_bounds__(256) void outln_kernel(
    const float* __restrict__ A, const float* __restrict__ Wo,
    const float* __restrict__ bo, const float* __restrict__ h,
    const float* __restrict__ gamma, const float* __restrict__ beta,
    float* __restrict__ out, int N)
{
    __shared__ float hs[64 * LDS_S];
    __shared__ float ws[64 * LDS_S];
    const int t = threadIdx.x;
    const int row0 = blockIdx.x * 64;

    const float* ablk = A + (size_t)row0 * 128;
    #pragma unroll
    for (int jj = 0; jj < 8; ++jj) {
        int e = t * 4 + jj * 1024;
        int rr = e >> 7, cc = e & 127;
        float4 val = make_float4(0.f, 0.f, 0.f, 0.f);
        if (row0 + rr < N) val = *(const float4*)(ablk + e);
        *(float4*)&hs[rr * LDS_S + cc] = val;
    }

    const int r = t >> 4, c = t & 15;

    float acc[4][8];
    #pragma unroll
    for (int i = 0; i < 4; ++i)
        #pragma unroll
        for (int j = 0; j < 8; ++j) acc[i][j] = 0.f;

    for (int half = 0; half < 2; ++half) {
        __syncthreads();
        const float* Wh = Wo + half * 64 * 128;
        #pragma unroll
        for (int jj = 0; jj < 8; ++jj) {
            int e = t * 4 + jj * 1024;
            int o = e >> 7, kk = e & 127;
            *(float4*)&ws[o * LDS_S + kk] = *(const float4*)(Wh + e);
        }
        __syncthreads();

        for (int k = 0; k < 128; k += 4) {
            float4 a[4], b[4];
            #pragma unroll
            for (int i = 0; i < 4; ++i)
                a[i] = *(const float4*)&hs[(4 * r + i) * LDS_S + k];
            #pragma unroll
            for (int j = 0; j < 4; ++j)
                b[j] = *(const float4*)&ws[(c + 16 * j) * LDS_S + k];
            #pragma unroll
            for (int i = 0; i < 4; ++i)
                #pragma unroll
                for (int j = 0; j < 4; ++j) {
                    float* ac = &acc[i][half * 4 + j];
                    *ac += a[i].x * b[j].x;
                    *ac += a[i].y * b[j].y;
                    *ac += a[i].z * b[j].z;
                    *ac += a[i].w * b[j].w;
                }
        }
    }

    // epilogue: bias + residual + LayerNorm
    float gam[8], bet[8], bov[8];
    #pragma unroll
    for (int j = 0; j < 8; ++j) {
        int col = ((j >> 2) << 6) + ((j & 3) << 4) + c;
        gam[j] = gamma[col];
        bet[j] = beta[col];
        bov[j] = bo[col];
    }

    #pragma unroll
    for (int i = 0; i < 4; ++i) {
        int row = row0 + 4 * r + i;
        const float* hrow = h + (size_t)row * 128;
        float x[8];
        float s = 0.f, s2 = 0.f;
        #pragma unroll
        for (int j = 0; j < 8; ++j) {
            int col = ((j >> 2) << 6) + ((j & 3) << 4) + c;
            float res = (row < N) ? hrow[col] : 0.f;
            float xx = acc[i][j] + bov[j] + res;
            x[j] = xx;
            s += xx;
            s2 += xx * xx;
        }
        // reduce over the 16 col-lanes (lane = 16*(r&3)+c, xor bits 1..8 vary c)
        #pragma unroll
        for (int d = 1; d < 16; d <<= 1) {
            s  += __shfl_xor(s,  d);
            s2 += __shfl_xor(s2, d);
        }
        float mu  = s * (1.f / 128.f);
        float var = s2 * (1.f / 128.f) - mu * mu;
        float rstd = rsqrtf(var + 1e-5f);
        if (row < N) {
            #pragma unroll
            for (int j = 0; j < 8; ++j) {
                int col = ((j >> 2) << 6) + ((j & 3) << 4) + c;
                out[(size_t)row * 128 + col] = (x[j] - mu) * rstd * gam[j] + bet[j];
            }
        }
    }
}

extern "C" void kernel_launch(void* const* d_in, const int* in_sizes, int n_in,
                              void* d_out, int out_size, void* d_ws, size_t ws_size,
                              hipStream_t stream) {
    const float* h   = (const float*)d_in[0];
    const int*   nbr = (const int*)  d_in[1];
    const float* Wq  = (const float*)d_in[2];
    const float* Wk  = (const float*)d_in[3];
    const float* Wv  = (const float*)d_in[4];
    const float* Wo  = (const float*)d_in[5];
    const float* bo  = (const float*)d_in[6];
    const float* gam = (const float*)d_in[7];
    const float* bet = (const float*)d_in[8];

    const int N = in_sizes[0] / 128;

    float* Q = (float*)d_ws;
    float* K = Q + (size_t)N * 128;
    float* V = K + (size_t)N * 128;
    float* A = Q;                 // alias: Q[n] fully consumed before A[n] write
    float* out = (float*)d_out;

    const int nbGemm = (N + 63) / 64;
    const int nbAttn = (N + 3) / 4;

    qkv_kernel<<<nbGemm, 256, 0, stream>>>(h, Wq, Wk, Wv, Q, K, V, N);
    attn_kernel<<<nbAttn, 256, 0, stream>>>(Q, K, V, nbr, A, N);
    outln_kernel<<<nbGemm, 256, 0, stream>>>(A, Wo, bo, h, gam, bet, out, N);
}

// Round 2
// 423.098 us; speedup vs baseline: 1.3668x; 1.3668x over previous
//
#include <hip/hip_runtime.h>

// R2: GEMMs via MFMA bf16x3 split (fp32-accurate), no LDS (frags direct from
// global, weights pre-split hi/lo bf16 by prep kernel). attn: V bf16, K fp32.
// Key: A and B MFMA fragments loaded with the SAME slot->k mapping (lane holds
// 8 contiguous k) => correct for any HW k-permutation since A/B layouts mirror.

typedef short bf16x8 __attribute__((ext_vector_type(8)));
typedef float f32x4  __attribute__((ext_vector_type(4)));

__device__ __forceinline__ ushort f2bf(float f) {   // RTN-even, no NaN handling
    uint u = __builtin_bit_cast(uint, f);
    u += 0x7fffu + ((u >> 16) & 1u);
    return (ushort)(u >> 16);
}
__device__ __forceinline__ float bf2f(ushort b) {
    uint u = ((uint)b) << 16;
    return __builtin_bit_cast(float, u);
}

// ---------------------------------------------------------------------------
// prep: split Wq,Wk,Wv,Wo (fp32 [128][128]) into hi/lo bf16 arrays.
// Whl layout: mat m at m*32768: [0,16384) = hi, [16384,32768) = lo. Row-major.
// ---------------------------------------------------------------------------
__global__ __launch_bounds__(256) void prep_kernel(
    const float* __restrict__ Wq, const float* __restrict__ Wk,
    const float* __restrict__ Wv, const float* __restrict__ Wo,
    ushort* __restrict__ Whl)
{
    int e = blockIdx.x * 256 + threadIdx.x;        // 0..65535
    const float* W[4] = {Wq, Wk, Wv, Wo};
    int m = e >> 14, i = e & 16383;
    float x = W[m][i];
    ushort hi = f2bf(x);
    ushort lo = f2bf(x - bf2f(hi));
    Whl[m * 32768 + i] = hi;
    Whl[m * 32768 + 16384 + i] = lo;
}

// ---------------------------------------------------------------------------
// qkv: Q=h@Wq^T (fp32 out), K=h@Wk^T (fp32 out), V=h@Wv^T (bf16 out).
// Block = 256 thr = 4 waves; wave owns 32 rows (2 MFMA row-tiles) x 128 cols
// (8 n-tiles). K=128 -> 4 MFMA k-steps; x3 split MFMAs. A-frags (h hi/lo)
// loaded+converted once, reused for all 3 mats. B-frags: 16B loads from Whl.
// ---------------------------------------------------------------------------
__global__ __launch_bounds__(256) void qkv_kernel(
    const float* __restrict__ h, const ushort* __restrict__ Whl,
    float* __restrict__ Q, float* __restrict__ Kf, ushort* __restrict__ Vb,
    int N)
{
    const int wave = threadIdx.x >> 6;
    const int lane = threadIdx.x & 63;
    const int lg = lane >> 4;        // k-group 0..3
    const int lr = lane & 15;        // A row / B col within tile
    const int r0 = blockIdx.x * 128 + wave * 32;

    // ---- load + split A fragments: rt in {0,1}, k0 in {0..3} ----
    bf16x8 ahi[2][4], alo[2][4];
    #pragma unroll
    for (int rt = 0; rt < 2; ++rt) {
        int row = r0 + rt * 16 + lr;
        bool ok = row < N;
        const float* hp = h + (size_t)row * 128 + lg * 8;
        #pragma unroll
        for (int k0 = 0; k0 < 4; ++k0) {
            float4 x0 = make_float4(0.f, 0.f, 0.f, 0.f), x1 = x0;
            if (ok) {
                x0 = *(const float4*)(hp + k0 * 32);
                x1 = *(const float4*)(hp + k0 * 32 + 4);
            }
            float xs[8] = {x0.x, x0.y, x0.z, x0.w, x1.x, x1.y, x1.z, x1.w};
            bf16x8 H, L;
            #pragma unroll
            for (int i = 0; i < 8; ++i) {
                ushort hb = f2bf(xs[i]);
                H[i] = (short)hb;
                L[i] = (short)f2bf(xs[i] - bf2f(hb));
            }
            ahi[rt][k0] = H; alo[rt][k0] = L;
        }
    }

    #pragma unroll
    for (int m = 0; m < 3; ++m) {
        const ushort* Whi = Whl + m * 32768;
        const ushort* Wlo = Whi + 16384;
        f32x4 acc[2][8];
        #pragma unroll
        for (int rt = 0; rt < 2; ++rt)
            #pragma unroll
            for (int n = 0; n < 8; ++n)
                acc[rt][n] = f32x4{0.f, 0.f, 0.f, 0.f};

        #pragma unroll
        for (int n = 0; n < 8; ++n) {
            size_t boff = (size_t)(n * 16 + lr) * 128 + lg * 8;
            #pragma unroll
            for (int k0 = 0; k0 < 4; ++k0) {
                bf16x8 bh = *(const bf16x8*)(Whi + boff + k0 * 32);
                bf16x8 bl = *(const bf16x8*)(Wlo + boff + k0 * 32);
                #pragma unroll
                for (int rt = 0; rt < 2; ++rt) {
                    acc[rt][n] = __builtin_amdgcn_mfma_f32_16x16x32_bf16(ahi[rt][k0], bh, acc[rt][n], 0, 0, 0);
                    acc[rt][n] = __builtin_amdgcn_mfma_f32_16x16x32_bf16(ahi[rt][k0], bl, acc[rt][n], 0, 0, 0);
                    acc[rt][n] = __builtin_amdgcn_mfma_f32_16x16x32_bf16(alo[rt][k0], bh, acc[rt][n], 0, 0, 0);
                }
            }
        }
        // C/D layout (m89): col = lane&15, row = (lane>>4)*4 + reg
        #pragma unroll
        for (int rt = 0; rt < 2; ++rt)
            #pragma unroll
            for (int reg = 0; reg < 4; ++reg) {
                int row = r0 + rt * 16 + lg * 4 + reg;
                if (row < N) {
                    #pragma unroll
                    for (int n = 0; n < 8; ++n) {
                        int col = n * 16 + lr;
                        float v = acc[rt][n][reg];
                        if (m == 0)      Q [(size_t)row * 128 + col] = v;
                        else if (m == 1) Kf[(size_t)row * 128 + col] = v;
                        else             Vb[(size_t)row * 128 + col] = f2bf(v);
                    }
                }
            }
    }
}

// ---------------------------------------------------------------------------
// attn: one wave per node; lane owns dims (2l, 2l+1); head = 8-lane group.
// K gathered fp32, V gathered bf16 (dword = 2 dims). A aliases Q (safe: wave
// reads only its own Q row, fully, before the A store).
// ---------------------------------------------------------------------------
__global__ __launch_bounds__(256) void attn_kernel(
    const float* Q, const float* __restrict__ Kf, const ushort* __restrict__ Vb,
    const int* __restrict__ nbr, float* A, int N)
{
    int gid = blockIdx.x * blockDim.x + threadIdx.x;
    int n = gid >> 6;
    int lane = threadIdx.x & 63;
    if (n >= N) return;

    float2 q = *(const float2*)&Q[(size_t)n * 128 + 2 * lane];

    int idx[16];
    #pragma unroll
    for (int j = 0; j < 16; ++j) idx[j] = nbr[n * 16 + j];

    float logit[16];
    #pragma unroll
    for (int j = 0; j < 16; ++j) {
        float2 kv = *(const float2*)&Kf[(size_t)idx[j] * 128 + 2 * lane];
        float s = q.x * kv.x + q.y * kv.y;
        s += __shfl_xor(s, 1);
        s += __shfl_xor(s, 2);
        s += __shfl_xor(s, 4);
        logit[j] = s * 0.25f;                       // D^-0.5
    }

    float m = logit[0];
    #pragma unroll
    for (int j = 1; j < 16; ++j) m = fmaxf(m, logit[j]);
    float sum = 0.f;
    #pragma unroll
    for (int j = 0; j < 16; ++j) { logit[j] = __expf(logit[j] - m); sum += logit[j]; }
    float inv = 1.f / sum;

    float2 acc = make_float2(0.f, 0.f);
    #pragma unroll
    for (int j = 0; j < 16; ++j) {
        uint u = *(const uint*)(Vb + (size_t)idx[j] * 128 + 2 * lane);
        float p = logit[j] * inv;
        acc.x += p * bf2f((ushort)(u & 0xffffu));
        acc.y += p * bf2f((ushort)(u >> 16));
    }
    *(float2*)&A[(size_t)n * 128 + 2 * lane] = acc;
}

// ---------------------------------------------------------------------------
// outln: out = LN(h + A@Wo^T + bo)*gamma + beta.  Same MFMA structure as qkv
// (mat 3 of Whl); epilogue does bias+residual then per-row mean/var via
// shfl_xor over the 16 col-lanes of each row group.
// ---------------------------------------------------------------------------
__global__ __launch_bounds__(256) void outln_kernel(
    const float* __restrict__ A, const ushort* __restrict__ Whl,
    const float* __restrict__ bo, const float* __restrict__ h,
    const float* __restrict__ gamma, const float* __restrict__ beta,
    float* __restrict__ out, int N)
{
    const int wave = threadIdx.x >> 6;
    const int lane = threadIdx.x & 63;
    const int lg = lane >> 4;
    const int lr = lane & 15;
    const int r0 = blockIdx.x * 128 + wave * 32;

    bf16x8 ahi[2][4], alo[2][4];
    #pragma unroll
    for (int rt = 0; rt < 2; ++rt) {
        int row = r0 + rt * 16 + lr;
        bool ok = row < N;
        const float* ap = A + (size_t)row * 128 + lg * 8;
        #pragma unroll
        for (int k0 = 0; k0 < 4; ++k0) {
            float4 x0 = make_float4(0.f, 0.f, 0.f, 0.f), x1 = x0;
            if (ok) {
                x0 = *(const float4*)(ap + k0 * 32);
                x1 = *(const float4*)(ap + k0 * 32 + 4);
            }
            float xs[8] = {x0.x, x0.y, x0.z, x0.w, x1.x, x1.y, x1.z, x1.w};
            bf16x8 H, L;
            #pragma unroll
            for (int i = 0; i < 8; ++i) {
                ushort hb = f2bf(xs[i]);
                H[i] = (short)hb;
                L[i] = (short)f2bf(xs[i] - bf2f(hb));
            }
            ahi[rt][k0] = H; alo[rt][k0] = L;
        }
    }

    const ushort* Whi = Whl + 3 * 32768;
    const ushort* Wlo = Whi + 16384;
    f32x4 acc[2][8];
    #pragma unroll
    for (int rt = 0; rt < 2; ++rt)
        #pragma unroll
        for (int n = 0; n < 8; ++n)
            acc[rt][n] = f32x4{0.f, 0.f, 0.f, 0.f};

    #pragma unroll
    for (int n = 0; n < 8; ++n) {
        size_t boff = (size_t)(n * 16 + lr) * 128 + lg * 8;
        #pragma unroll
        for (int k0 = 0; k0 < 4; ++k0) {
            bf16x8 bh = *(const bf16x8*)(Whi + boff + k0 * 32);
            bf16x8 bl = *(const bf16x8*)(Wlo + boff + k0 * 32);
            #pragma unroll
            for (int rt = 0; rt < 2; ++rt) {
                acc[rt][n] = __builtin_amdgcn_mfma_f32_16x16x32_bf16(ahi[rt][k0], bh, acc[rt][n], 0, 0, 0);
                acc[rt][n] = __builtin_amdgcn_mfma_f32_16x16x32_bf16(ahi[rt][k0], bl, acc[rt][n], 0, 0, 0);
                acc[rt][n] = __builtin_amdgcn_mfma_f32_16x16x32_bf16(alo[rt][k0], bh, acc[rt][n], 0, 0, 0);
            }
        }
    }

    // per-lane epilogue params for its 8 columns
    float bo_r[8], g_r[8], b_r[8];
    #pragma unroll
    for (int n = 0; n < 8; ++n) {
        int col = n * 16 + lr;
        bo_r[n] = bo[col]; g_r[n] = gamma[col]; b_r[n] = beta[col];
    }

    #pragma unroll
    for (int rt = 0; rt < 2; ++rt) {
        float s[4] = {0.f, 0.f, 0.f, 0.f}, s2[4] = {0.f, 0.f, 0.f, 0.f};
        #pragma unroll
        for (int reg = 0; reg < 4; ++reg) {
            int row = r0 + rt * 16 + lg * 4 + reg;
            bool ok = row < N;
            const float* hrow = h + (size_t)row * 128;
            #pragma unroll
            for (int n = 0; n < 8; ++n) {
                int col = n * 16 + lr;
                float xx = acc[rt][n][reg] + bo_r[n] + (ok ? hrow[col] : 0.f);
                acc[rt][n][reg] = xx;
                s[reg] += xx;
                s2[reg] += xx * xx;
            }
        }
        // reduce across the 16 col-lanes (xor bits 0..3 keep lg fixed)
        #pragma unroll
        for (int reg = 0; reg < 4; ++reg) {
            float a = s[reg], b2 = s2[reg];
            #pragma unroll
            for (int d = 1; d < 16; d <<= 1) {
                a  += __shfl_xor(a,  d);
                b2 += __shfl_xor(b2, d);
            }
            float mu  = a * (1.f / 128.f);
            float var = b2 * (1.f / 128.f) - mu * mu;
            float rstd = rsqrtf(var + 1e-5f);
            int row = r0 + rt * 16 + lg * 4 + reg;
            if (row < N) {
                #pragma unroll
                for (int n = 0; n < 8; ++n) {
                    int col = n * 16 + lr;
                    out[(size_t)row * 128 + col] =
                        (acc[rt][n][reg] - mu) * rstd * g_r[n] + b_r[n];
                }
            }
        }
    }
}

extern "C" void kernel_launch(void* const* d_in, const int* in_sizes, int n_in,
                              void* d_out, int out_size, void* d_ws, size_t ws_size,
                              hipStream_t stream) {
    const float* h   = (const float*)d_in[0];
    const int*   nbr = (const int*)  d_in[1];
    const float* Wq  = (const float*)d_in[2];
    const float* Wk  = (const float*)d_in[3];
    const float* Wv  = (const float*)d_in[4];
    const float* Wo  = (const float*)d_in[5];
    const float* bo  = (const float*)d_in[6];
    const float* gam = (const float*)d_in[7];
    const float* bet = (const float*)d_in[8];

    const int N = in_sizes[0] / 128;

    // ws layout: Q f32 | Kf f32 | Vb bf16 | Whl bf16   (A aliases Q)
    float*  Q   = (float*)d_ws;
    float*  Kf  = Q + (size_t)N * 128;
    ushort* Vb  = (ushort*)(Kf + (size_t)N * 128);
    ushort* Whl = Vb + (size_t)N * 128;
    float*  A   = Q;
    float*  out = (float*)d_out;

    prep_kernel<<<256, 256, 0, stream>>>(Wq, Wk, Wv, Wo, Whl);
    const int nbGemm = (N + 127) / 128;
    qkv_kernel<<<nbGemm, 256, 0, stream>>>(h, Whl, Q, Kf, Vb, N);
    attn_kernel<<<(N + 3) / 4, 256, 0, stream>>>(Q, Kf, Vb, nbr, A, N);
    outln_kernel<<<nbGemm, 256, 0, stream>>>(A, Whl, bo, h, gam, bet, out, N);
}

// Round 4
// 359.584 us; speedup vs baseline: 1.6082x; 1.1766x over previous
//
#include <hip/hip_runtime.h>

// R3 (resubmit — R3 bench never acquired a GPU): all intermediates bf16.
// KV packed per-node as one 512B row [K0..K127 | V0..V127] so the 16-neighbor
// gather touches one base/neighbor and every fetched line is used exactly
// once. A stored bf16 -> outln GEMM A-operand is exact bf16 (2 MFMAs/tile).
// GEMMs: MFMA bf16x3 split (qkv) / bf16x2 (outln), fragments loaded directly
// from global with identical A/B slot->k mapping (HW-verified in R2).

typedef short bf16x8 __attribute__((ext_vector_type(8)));
typedef float f32x4  __attribute__((ext_vector_type(4)));

__device__ __forceinline__ ushort f2bf(float f) {   // RTN-even
    uint u = __builtin_bit_cast(uint, f);
    u += 0x7fffu + ((u >> 16) & 1u);
    return (ushort)(u >> 16);
}
__device__ __forceinline__ float bf2f(ushort b) {
    uint u = ((uint)b) << 16;
    return __builtin_bit_cast(float, u);
}

// ---------------------------------------------------------------------------
// prep: split Wq,Wk,Wv,Wo (fp32 [128][128]) into hi/lo bf16.
// Whl: mat m at m*32768: [0,16384)=hi, [16384,32768)=lo.
// ---------------------------------------------------------------------------
__global__ __launch_bounds__(256) void prep_kernel(
    const float* __restrict__ Wq, const float* __restrict__ Wk,
    const float* __restrict__ Wv, const float* __restrict__ Wo,
    ushort* __restrict__ Whl)
{
    int e = blockIdx.x * 256 + threadIdx.x;        // 0..65535
    const float* W[4] = {Wq, Wk, Wv, Wo};
    int m = e >> 14, i = e & 16383;
    float x = W[m][i];
    ushort hi = f2bf(x);
    ushort lo = f2bf(x - bf2f(hi));
    Whl[m * 32768 + i] = hi;
    Whl[m * 32768 + 16384 + i] = lo;
}

// ---------------------------------------------------------------------------
// qkv: Qb = bf16(h@Wq^T); KVb[n] = [bf16(h@Wk^T) | bf16(h@Wv^T)] (512B row).
// Block = 4 waves; wave owns 32 rows x 128 cols. bf16x3 split MFMAs.
// ---------------------------------------------------------------------------
__global__ __launch_bounds__(256) void qkv_kernel(
    const float* __restrict__ h, const ushort* __restrict__ Whl,
    ushort* __restrict__ Qb, ushort* __restrict__ KVb, int N)
{
    const int wave = threadIdx.x >> 6;
    const int lane = threadIdx.x & 63;
    const int lg = lane >> 4;        // k-group 0..3
    const int lr = lane & 15;        // A row / B col within tile
    const int r0 = blockIdx.x * 128 + wave * 32;

    // load + split A fragments (reused for all 3 mats)
    bf16x8 ahi[2][4], alo[2][4];
    #pragma unroll
    for (int rt = 0; rt < 2; ++rt) {
        int row = r0 + rt * 16 + lr;
        bool ok = row < N;
        const float* hp = h + (size_t)row * 128 + lg * 8;
        #pragma unroll
        for (int k0 = 0; k0 < 4; ++k0) {
            float4 x0 = make_float4(0.f, 0.f, 0.f, 0.f), x1 = x0;
            if (ok) {
                x0 = *(const float4*)(hp + k0 * 32);
                x1 = *(const float4*)(hp + k0 * 32 + 4);
            }
            float xs[8] = {x0.x, x0.y, x0.z, x0.w, x1.x, x1.y, x1.z, x1.w};
            bf16x8 H, L;
            #pragma unroll
            for (int i = 0; i < 8; ++i) {
                ushort hb = f2bf(xs[i]);
                H[i] = (short)hb;
                L[i] = (short)f2bf(xs[i] - bf2f(hb));
            }
            ahi[rt][k0] = H; alo[rt][k0] = L;
        }
    }

    #pragma unroll
    for (int m = 0; m < 3; ++m) {
        const ushort* Whi = Whl + m * 32768;
        const ushort* Wlo = Whi + 16384;
        f32x4 acc[2][8];
        #pragma unroll
        for (int rt = 0; rt < 2; ++rt)
            #pragma unroll
            for (int n = 0; n < 8; ++n)
                acc[rt][n] = f32x4{0.f, 0.f, 0.f, 0.f};

        #pragma unroll
        for (int n = 0; n < 8; ++n) {
            size_t boff = (size_t)(n * 16 + lr) * 128 + lg * 8;
            #pragma unroll
            for (int k0 = 0; k0 < 4; ++k0) {
                bf16x8 bh = *(const bf16x8*)(Whi + boff + k0 * 32);
                bf16x8 bl = *(const bf16x8*)(Wlo + boff + k0 * 32);
                #pragma unroll
                for (int rt = 0; rt < 2; ++rt) {
                    acc[rt][n] = __builtin_amdgcn_mfma_f32_16x16x32_bf16(ahi[rt][k0], bh, acc[rt][n], 0, 0, 0);
                    acc[rt][n] = __builtin_amdgcn_mfma_f32_16x16x32_bf16(ahi[rt][k0], bl, acc[rt][n], 0, 0, 0);
                    acc[rt][n] = __builtin_amdgcn_mfma_f32_16x16x32_bf16(alo[rt][k0], bh, acc[rt][n], 0, 0, 0);
                }
            }
        }
        // C/D layout: col = lane&15, row = (lane>>4)*4 + reg
        #pragma unroll
        for (int rt = 0; rt < 2; ++rt)
            #pragma unroll
            for (int reg = 0; reg < 4; ++reg) {
                int row = r0 + rt * 16 + lg * 4 + reg;
                if (row < N) {
                    #pragma unroll
                    for (int n = 0; n < 8; ++n) {
                        int col = n * 16 + lr;
                        ushort v = f2bf(acc[rt][n][reg]);
                        if (m == 0)      Qb [(size_t)row * 128 + col] = v;
                        else if (m == 1) KVb[(size_t)row * 256 + col] = v;
                        else             KVb[(size_t)row * 256 + 128 + col] = v;
                    }
                }
            }
    }
}

// ---------------------------------------------------------------------------
// attn: one wave per node; lane owns dims (2l,2l+1); head = 8-lane group.
// K phase reads bytes [0,256) of the neighbor's KV row, V phase [256,512):
// each gathered line used exactly once. Ab aliases Qb (wave reads only its
// own Q row, fully, before the A store).
// ---------------------------------------------------------------------------
__global__ __launch_bounds__(256) void attn_kernel(
    const ushort* Qb, const ushort* __restrict__ KVb,
    const int* __restrict__ nbr, ushort* Ab, int N)
{
    int gid = blockIdx.x * blockDim.x + threadIdx.x;
    int n = gid >> 6;
    int lane = threadIdx.x & 63;
    if (n >= N) return;

    uint qw = *(const uint*)(Qb + (size_t)n * 128 + 2 * lane);
    float qx = bf2f((ushort)(qw & 0xffffu));
    float qy = bf2f((ushort)(qw >> 16));

    int idx[16];
    #pragma unroll
    for (int j = 0; j < 16; ++j) idx[j] = nbr[n * 16 + j];

    float logit[16];
    #pragma unroll
    for (int j = 0; j < 16; ++j) {
        uint kw = *(const uint*)(KVb + (size_t)idx[j] * 256 + 2 * lane);
        float s = qx * bf2f((ushort)(kw & 0xffffu))
                + qy * bf2f((ushort)(kw >> 16));
        s += __shfl_xor(s, 1);
        s += __shfl_xor(s, 2);
        s += __shfl_xor(s, 4);
        logit[j] = s * 0.25f;                       // D^-0.5
    }

    float m = logit[0];
    #pragma unroll
    for (int j = 1; j < 16; ++j) m = fmaxf(m, logit[j]);
    float sum = 0.f;
    #pragma unroll
    for (int j = 0; j < 16; ++j) { logit[j] = __expf(logit[j] - m); sum += logit[j]; }
    float inv = 1.f / sum;

    float ax = 0.f, ay = 0.f;
    #pragma unroll
    for (int j = 0; j < 16; ++j) {
        uint vw = *(const uint*)(KVb + (size_t)idx[j] * 256 + 128 + 2 * lane);
        float p = logit[j] * inv;
        ax += p * bf2f((ushort)(vw & 0xffffu));
        ay += p * bf2f((ushort)(vw >> 16));
    }
    uint out = (uint)f2bf(ax) | ((uint)f2bf(ay) << 16);
    *(uint*)(Ab + (size_t)n * 128 + 2 * lane) = out;
}

// ---------------------------------------------------------------------------
// outln: out = LN(h + A@Wo^T + bo)*gamma + beta.  A is exact bf16 ->
// 2 MFMAs/tile (a*Whi + a*Wlo).
// ---------------------------------------------------------------------------
__global__ __launch_bounds__(256) void outln_kernel(
    const ushort* __restrict__ Ab, const ushort* __restrict__ Whl,
    const float* __restrict__ bo, const float* __restrict__ h,
    const float* __restrict__ gamma, const float* __restrict__ beta,
    float* __restrict__ out, int N)
{
    const int wave = threadIdx.x >> 6;
    const int lane = threadIdx.x & 63;
    const int lg = lane >> 4;
    const int lr = lane & 15;
    const int r0 = blockIdx.x * 128 + wave * 32;

    bf16x8 af[2][4];
    #pragma unroll
    for (int rt = 0; rt < 2; ++rt) {
        int row = r0 + rt * 16 + lr;
        bool ok = row < N;
        const ushort* ap = Ab + (size_t)row * 128 + lg * 8;
        #pragma unroll
        for (int k0 = 0; k0 < 4; ++k0) {
            bf16x8 a = bf16x8{0,0,0,0,0,0,0,0};
            if (ok) a = *(const bf16x8*)(ap + k0 * 32);
            af[rt][k0] = a;
        }
    }

    const ushort* Whi = Whl + 3 * 32768;
    const ushort* Wlo = Whi + 16384;
    f32x4 acc[2][8];
    #pragma unroll
    for (int rt = 0; rt < 2; ++rt)
        #pragma unroll
        for (int n = 0; n < 8; ++n)
            acc[rt][n] = f32x4{0.f, 0.f, 0.f, 0.f};

    #pragma unroll
    for (int n = 0; n < 8; ++n) {
        size_t boff = (size_t)(n * 16 + lr) * 128 + lg * 8;
        #pragma unroll
        for (int k0 = 0; k0 < 4; ++k0) {
            bf16x8 bh = *(const bf16x8*)(Whi + boff + k0 * 32);
            bf16x8 bl = *(const bf16x8*)(Wlo + boff + k0 * 32);
            #pragma unroll
            for (int rt = 0; rt < 2; ++rt) {
                acc[rt][n] = __builtin_amdgcn_mfma_f32_16x16x32_bf16(af[rt][k0], bh, acc[rt][n], 0, 0, 0);
                acc[rt][n] = __builtin_amdgcn_mfma_f32_16x16x32_bf16(af[rt][k0], bl, acc[rt][n], 0, 0, 0);
            }
        }
    }

    float bo_r[8], g_r[8], b_r[8];
    #pragma unroll
    for (int n = 0; n < 8; ++n) {
        int col = n * 16 + lr;
        bo_r[n] = bo[col]; g_r[n] = gamma[col]; b_r[n] = beta[col];
    }

    #pragma unroll
    for (int rt = 0; rt < 2; ++rt) {
        float s[4] = {0.f, 0.f, 0.f, 0.f}, s2[4] = {0.f, 0.f, 0.f, 0.f};
        #pragma unroll
        for (int reg = 0; reg < 4; ++reg) {
            int row = r0 + rt * 16 + lg * 4 + reg;
            bool ok = row < N;
            const float* hrow = h + (size_t)row * 128;
            #pragma unroll
            for (int n = 0; n < 8; ++n) {
                int col = n * 16 + lr;
                float xx = acc[rt][n][reg] + bo_r[n] + (ok ? hrow[col] : 0.f);
                acc[rt][n][reg] = xx;
                s[reg] += xx;
                s2[reg] += xx * xx;
            }
        }
        #pragma unroll
        for (int reg = 0; reg < 4; ++reg) {
            float a = s[reg], b2 = s2[reg];
            #pragma unroll
            for (int d = 1; d < 16; d <<= 1) {
                a  += __shfl_xor(a,  d);
                b2 += __shfl_xor(b2, d);
            }
            float mu  = a * (1.f / 128.f);
            float var = b2 * (1.f / 128.f) - mu * mu;
            float rstd = rsqrtf(var + 1e-5f);
            int row = r0 + rt * 16 + lg * 4 + reg;
            if (row < N) {
                #pragma unroll
                for (int n = 0; n < 8; ++n) {
                    int col = n * 16 + lr;
                    out[(size_t)row * 128 + col] =
                        (acc[rt][n][reg] - mu) * rstd * g_r[n] + b_r[n];
                }
            }
        }
    }
}

extern "C" void kernel_launch(void* const* d_in, const int* in_sizes, int n_in,
                              void* d_out, int out_size, void* d_ws, size_t ws_size,
                              hipStream_t stream) {
    const float* h   = (const float*)d_in[0];
    const int*   nbr = (const int*)  d_in[1];
    const float* Wq  = (const float*)d_in[2];
    const float* Wk  = (const float*)d_in[3];
    const float* Wv  = (const float*)d_in[4];
    const float* Wo  = (const float*)d_in[5];
    const float* bo  = (const float*)d_in[6];
    const float* gam = (const float*)d_in[7];
    const float* bet = (const float*)d_in[8];

    const int N = in_sizes[0] / 128;

    // ws: Qb bf16 N*128 | KVb bf16 N*256 | Whl bf16 4*32768.  Ab aliases Qb.
    ushort* Qb  = (ushort*)d_ws;
    ushort* KVb = Qb + (size_t)N * 128;
    ushort* Whl = KVb + (size_t)N * 256;
    ushort* Ab  = Qb;
    float*  out = (float*)d_out;

    prep_kernel<<<256, 256, 0, stream>>>(Wq, Wk, Wv, Wo, Whl);
    const int nbGemm = (N + 127) / 128;
    qkv_kernel<<<nbGemm, 256, 0, stream>>>(h, Whl, Qb, KVb, N);
    attn_kernel<<<(N + 3) / 4, 256, 0, stream>>>(Qb, KVb, nbr, Ab, N);
    outln_kernel<<<nbGemm, 256, 0, stream>>>(Ab, Whl, bo, h, gam, bet, out, N);
}